// Round 9
// baseline (638.736 us; speedup 1.0000x reference)
//
#include <hip/hip_runtime.h>
#include <hip/hip_bf16.h>
#include <math.h>

// ---------------------------------------------------------------------------
// GCN predictor: 2x GCNConv(relu) -> mean pool + global feats -> MLP head
// N=100K nodes, E=3.2M directed edges, H=64.
// R9: parallel CSR build -- k_deg (global atomics) + two-level scan for pos
// + (NBK x 8)-grid bucket-sliced scatter with global cursor atomics (no LDS
// atomic chains; k_csr's 143us/13% occupancy fixed). Layer-2 back to R7's
// fused gather+shfl-matmul (the R8 split regressed).
// ---------------------------------------------------------------------------

#define BUCKET 256
#define MAXB   512   // max buckets / max chunks (needs n <= 131072)

// deg[d] += 1 over all edges (global atomics, L2-resident counters)
__global__ void k_deg(const int* __restrict__ dst, int E, int* __restrict__ deg) {
    int stride = gridDim.x * blockDim.x;
    for (int e = blockIdx.x * blockDim.x + threadIdx.x; e < E; e += stride)
        atomicAdd(&deg[dst[e]], 1);
}

// per-chunk bucket histogram: gcounts[chunk*NBK + bucket]
__global__ void k_hist(const int* __restrict__ dst, int E, int chunk,
                       int* __restrict__ gcounts, int NBK) {
    __shared__ int lcnt[MAXB];
    for (int i = threadIdx.x; i < NBK; i += blockDim.x) lcnt[i] = 0;
    __syncthreads();
    int e0 = blockIdx.x * chunk;
    int e1 = min(e0 + chunk, E);
    for (int e = e0 + threadIdx.x; e < e1; e += blockDim.x)
        atomicAdd(&lcnt[dst[e] >> 8], 1);
    __syncthreads();
    for (int b = threadIdx.x; b < NBK; b += blockDim.x)
        gcounts[blockIdx.x * NBK + b] = lcnt[b];
}

// single block: bucket_base[b] = exclusive scan of per-bucket totals
// also zero-inits the red[] accumulator (saves a memset dispatch)
__global__ void k_scanA(const int* __restrict__ gcounts, int* __restrict__ bucket_base,
                        float* __restrict__ red, int NBK, int NCH) {
    __shared__ int lds[MAXB];
    int t = threadIdx.x;
    if (t < 96) red[t] = 0.f;
    int tot = 0;
    if (t < NBK)
        for (int c = 0; c < NCH; ++c) tot += gcounts[c * NBK + t];
    lds[t] = tot;
    __syncthreads();
    for (int off = 1; off < MAXB; off <<= 1) {
        int add = (t >= off) ? lds[t - off] : 0;
        __syncthreads();
        lds[t] += add;
        __syncthreads();
    }
    if (t < NBK) bucket_base[t] = lds[t] - tot;
    if (t == NBK - 1) bucket_base[NBK] = lds[t];
}

// per bucket: scan counts across chunks, in place:
// gcounts[c*NBK+b] becomes the global slot base for (chunk c, bucket b)
__global__ void k_scanB(int* __restrict__ gcounts, const int* __restrict__ bucket_base,
                        int NBK, int NCH) {
    __shared__ int lds[MAXB];
    int b = blockIdx.x;
    int t = threadIdx.x;
    int v = (t < NCH) ? gcounts[t * NBK + b] : 0;
    lds[t] = v;
    __syncthreads();
    for (int off = 1; off < MAXB; off <<= 1) {
        int add = (t >= off) ? lds[t - off] : 0;
        __syncthreads();
        lds[t] += add;
        __syncthreads();
    }
    if (t < NCH) gcounts[t * NBK + b] = bucket_base[b] + lds[t] - v;
}

// scatter packed records (local_d<<17 | src) into bucket-grouped order
__global__ void k_bucketize(const int* __restrict__ src, const int* __restrict__ dst,
                            int E, int chunk, const int* __restrict__ gcounts,
                            int* __restrict__ records, int NBK) {
    __shared__ int lcur[MAXB];
    for (int b = threadIdx.x; b < NBK; b += blockDim.x)
        lcur[b] = gcounts[blockIdx.x * NBK + b];
    __syncthreads();
    int e0 = blockIdx.x * chunk;
    int e1 = min(e0 + chunk, E);
    for (int e = e0 + threadIdx.x; e < e1; e += blockDim.x) {
        int d = dst[e];
        int b = d >> 8;
        int rec = ((d & 255) << 17) | src[e];
        int slot = atomicAdd(&lcur[b], 1);
        records[slot] = rec;
    }
}

// two-level exclusive scan of deg, level 1: per-256-block sums
__global__ void k_blocksum(const int* __restrict__ deg, int* __restrict__ bsum, int n) {
    __shared__ int lds[256];
    int i = blockIdx.x * 256 + threadIdx.x;
    lds[threadIdx.x] = (i < n) ? deg[i] : 0;
    __syncthreads();
    for (int off = 128; off; off >>= 1) {
        if (threadIdx.x < off) lds[threadIdx.x] += lds[threadIdx.x + off];
        __syncthreads();
    }
    if (threadIdx.x == 0) bsum[blockIdx.x] = lds[0];
}

// level 2: exclusive scan of block sums (single block, nb <= 512)
__global__ void k_scanbsum(int* __restrict__ bsum, int nb) {
    __shared__ int lds[512];
    int t = threadIdx.x;
    int v = (t < nb) ? bsum[t] : 0;
    lds[t] = v;
    __syncthreads();
    for (int off = 1; off < 512; off <<= 1) {
        int add = (t >= off) ? lds[t - off] : 0;
        __syncthreads();
        lds[t] += add;
        __syncthreads();
    }
    if (t < nb) bsum[t] = lds[t] - v;   // exclusive
}

// level 3 per-node: pos/rowend/cursor + dinv + xs prescale + gf partials
__global__ void k_scan2(const int* __restrict__ deg, const int* __restrict__ bsum,
                        const float* __restrict__ x,
                        int* __restrict__ pos, int* __restrict__ rowend,
                        int* __restrict__ cursor, float* __restrict__ dinv,
                        float* __restrict__ xs, float* __restrict__ red, int n) {
    __shared__ int lds[256];
    int t = threadIdx.x;
    int i = blockIdx.x * 256 + t;
    int v = (i < n) ? deg[i] : 0;
    lds[t] = v;
    __syncthreads();
    for (int off = 1; off < 256; off <<= 1) {
        int add = (t >= off) ? lds[t - off] : 0;
        __syncthreads();
        lds[t] += add;
        __syncthreads();
    }
    float s2 = 0.f, s3 = 0.f, s4 = 0.f, sm0 = 0.f, sm1 = 0.f, sc = 0.f;
    if (i < n) {
        int p = bsum[blockIdx.x] + lds[t] - v;   // exclusive
        pos[i] = p;
        rowend[i] = p + v;
        cursor[i] = p;
        float d = rsqrtf((float)(v + 1));
        dinv[i] = d;
        float x0 = x[i * 5 + 0], x1 = x[i * 5 + 1], x2 = x[i * 5 + 2];
        float x3 = x[i * 5 + 3], x4 = x[i * 5 + 4];
        float4 o;
        o.x = x0 * d; o.y = x1 * d; o.z = x2 * d; o.w = x3 * d;
        ((float4*)xs)[i * 2] = o;
        xs[i * 8 + 4] = x4 * d;
        s2 = x2; s3 = x3; s4 = x4;
        if (x2 == 1.0f) { sm0 = x0; sm1 = x1; sc = 1.f; }
    }
#pragma unroll
    for (int off = 32; off; off >>= 1) {
        s2 += __shfl_down(s2, off);
        s3 += __shfl_down(s3, off);
        s4 += __shfl_down(s4, off);
        sm0 += __shfl_down(sm0, off);
        sm1 += __shfl_down(sm1, off);
        sc += __shfl_down(sc, off);
    }
    if ((t & 63) == 0) {
        atomicAdd(&red[64], s2);
        atomicAdd(&red[65], s3);
        atomicAdd(&red[66], s4);
        atomicAdd(&red[67], sm0);
        atomicAdd(&red[68], sm1);
        atomicAdd(&red[69], sc);
    }
}

// bucket-sliced scatter into per-node CSR: grid (NBK, SPLIT); global cursor
// atomics (L2-resident), writes land dense inside each bucket's region.
__global__ void k_scatter2(const int* __restrict__ records, const int* __restrict__ bucket_base,
                           int* __restrict__ cursor, int* __restrict__ ssrc) {
    int b = blockIdx.x;
    int j0 = bucket_base[b], j1 = bucket_base[b + 1];
    int stride = gridDim.y * blockDim.x;
    for (int j = j0 + blockIdx.y * blockDim.x + threadIdx.x; j < j1; j += stride) {
        int rec = records[j];
        int gnode = (b << 8) + (rec >> 17);
        int slot = atomicAdd(&cursor[gnode], 1);
        ssrc[slot] = rec & 131071;
    }
}

// 5-dim aggregation: agg5[i,:] = dinv[i] * ( sum_{s in N(i)} xs[s,:] + xs[i,:] )
// thread per node; xs is ~3MB -> L2-resident gathers
__global__ void k_agg5(const int* __restrict__ pos, const int* __restrict__ rowend,
                       const int* __restrict__ ssrc, const float* __restrict__ dinv,
                       const float* __restrict__ xs, float* __restrict__ agg5, int n) {
    int i = blockIdx.x * blockDim.x + threadIdx.x;
    if (i >= n) return;
    const float4* xs4 = (const float4*)xs;
    float4 a = xs4[i * 2];            // self term
    float a4 = xs[i * 8 + 4];
    int beg = pos[i], end = rowend[i];
    int j = beg;
    for (; j + 1 < end; j += 2) {
        int s0 = ssrc[j], s1 = ssrc[j + 1];
        float4 v0 = xs4[s0 * 2]; float w0 = xs[s0 * 8 + 4];
        float4 v1 = xs4[s1 * 2]; float w1 = xs[s1 * 8 + 4];
        a.x += v0.x + v1.x; a.y += v0.y + v1.y;
        a.z += v0.z + v1.z; a.w += v0.w + v1.w;
        a4 += w0 + w1;
    }
    for (; j < end; ++j) {
        int s = ssrc[j];
        float4 v = xs4[s * 2];
        a.x += v.x; a.y += v.y; a.z += v.z; a.w += v.w;
        a4 += xs[s * 8 + 4];
    }
    float dd = dinv[i];
    float4 o; o.x = a.x * dd; o.y = a.y * dd; o.z = a.z * dd; o.w = a.w * dd;
    ((float4*)agg5)[i * 2] = o;
    agg5[i * 8 + 4] = a4 * dd;
}

// h1s[i,f] = bf16( dinv[i] * relu( agg5[i,:] @ W1[:,f] + b1[f] ) )  (wave/node)
__global__ void k_h1(const float* __restrict__ agg5, const float* __restrict__ W1,
                     const float* __restrict__ b1, const float* __restrict__ dinv,
                     __hip_bfloat16* __restrict__ h1s, int n) {
    int t = blockIdx.x * blockDim.x + threadIdx.x;
    int i = t >> 6, f = t & 63;
    if (i >= n) return;
    float a0 = agg5[i * 8 + 0], a1 = agg5[i * 8 + 1], a2 = agg5[i * 8 + 2];
    float a3 = agg5[i * 8 + 3], a4 = agg5[i * 8 + 4];
    float v = a0 * W1[f] + a1 * W1[64 + f] + a2 * W1[128 + f]
            + a3 * W1[192 + f] + a4 * W1[256 + f] + b1[f];
    h1s[(size_t)i * 64 + f] = __float2bfloat16(dinv[i] * fmaxf(v, 0.f));
}

// Layer 2 fully fused, 4 nodes per wave interleaved (R7 version):
// gather prescaled bf16 h1s rows for 4 independent neighbor streams (lockstep,
// predicated), then 4 interleaved shfl matmuls (@W2+b2+relu), mean-pool reduce.
__global__ __launch_bounds__(256)
void k_l2fuse(const int* __restrict__ pos, const int* __restrict__ rowend,
              const int* __restrict__ ssrc, const float* __restrict__ dinv,
              const __hip_bfloat16* __restrict__ h1s, const float* __restrict__ W2,
              const float* __restrict__ b2, float* __restrict__ red, int n) {
    __shared__ float red64[64];
    int t = threadIdx.x, f = t & 63;
    if (t < 64) red64[t] = 0.f;
    __syncthreads();
    int w = blockIdx.x * (blockDim.x >> 6) + (t >> 6);
    int nw = gridDim.x * (blockDim.x >> 6);
    float bf = b2[f];
    float psum = 0.f;
    int nt = (n + 3) >> 2;
    for (int task = w; task < nt; task += nw) {
        int i0 = task * 4, i1 = i0 + 1, i2 = i0 + 2, i3 = i0 + 3;
        bool v1 = i1 < n, v2 = i2 < n, v3 = i3 < n;
        int p0 = pos[i0],            e0 = rowend[i0];
        int p1 = v1 ? pos[i1] : 0,   e1 = v1 ? rowend[i1] : 0;
        int p2 = v2 ? pos[i2] : 0,   e2 = v2 ? rowend[i2] : 0;
        int p3 = v3 ? pos[i3] : 0,   e3 = v3 ? rowend[i3] : 0;
        float a0 = __bfloat162float(h1s[(size_t)i0 * 64 + f]);
        float a1 = v1 ? __bfloat162float(h1s[(size_t)i1 * 64 + f]) : 0.f;
        float a2 = v2 ? __bfloat162float(h1s[(size_t)i2 * 64 + f]) : 0.f;
        float a3 = v3 ? __bfloat162float(h1s[(size_t)i3 * 64 + f]) : 0.f;
        int len = max(max(e0 - p0, e1 - p1), max(e2 - p2, e3 - p3));
#pragma unroll 2
        for (int m = 0; m < len; ++m) {
            int j0 = p0 + m, j1 = p1 + m, j2 = p2 + m, j3 = p3 + m;
            int s0 = ssrc[j0 < e0 ? j0 : 0];
            int s1 = ssrc[j1 < e1 ? j1 : 0];
            int s2 = ssrc[j2 < e2 ? j2 : 0];
            int s3 = ssrc[j3 < e3 ? j3 : 0];
            float g0 = __bfloat162float(h1s[(size_t)s0 * 64 + f]);
            float g1 = __bfloat162float(h1s[(size_t)s1 * 64 + f]);
            float g2 = __bfloat162float(h1s[(size_t)s2 * 64 + f]);
            float g3 = __bfloat162float(h1s[(size_t)s3 * 64 + f]);
            if (j0 < e0) a0 += g0;
            if (j1 < e1) a1 += g1;
            if (j2 < e2) a2 += g2;
            if (j3 < e3) a3 += g3;
        }
        // conv2: out_k[f] = relu( dinv * sum_kk a_k[kk]*W2[kk,f] + b2[f] )
        float q0 = 0.f, q1 = 0.f, q2 = 0.f, q3 = 0.f;
#pragma unroll 8
        for (int k = 0; k < 64; ++k) {
            float w2v = W2[k * 64 + f];
            q0 += __shfl(a0, k) * w2v;
            q1 += __shfl(a1, k) * w2v;
            q2 += __shfl(a2, k) * w2v;
            q3 += __shfl(a3, k) * w2v;
        }
        psum += fmaxf(q0 * dinv[i0] + bf, 0.f);
        if (v1) psum += fmaxf(q1 * dinv[i1] + bf, 0.f);
        if (v2) psum += fmaxf(q2 * dinv[i2] + bf, 0.f);
        if (v3) psum += fmaxf(q3 * dinv[i3] + bf, 0.f);
    }
    atomicAdd(&red64[f], psum);
    __syncthreads();
    if (t < 64) atomicAdd(&red[t], red64[t]);
}

// Final head: emb = [mean(h2), gf(6)] (70), MLP 70->32->2, 2+3*sigmoid
__global__ void k_head(const float* __restrict__ red,
                       const float* __restrict__ l1w, const float* __restrict__ l1b,
                       const float* __restrict__ l2w, const float* __restrict__ l2b,
                       float* __restrict__ out, int n) {
    __shared__ float emb[70];
    __shared__ float hid[32];
    int t = threadIdx.x;
    if (t < 64) emb[t] = red[t] / (float)n;
    if (t == 0) {
        float n_comp = red[64], n_and = red[65], n_or = red[66];
        float cnt = red[69];
        float safe = fmaxf(cnt, 1.f);
        emb[64] = n_comp;
        emb[65] = n_and;
        emb[66] = n_or;
        emb[67] = n_and + n_or;
        emb[68] = cnt > 0.f ? red[67] / safe : 0.f;
        emb[69] = cnt > 0.f ? red[68] / safe : 0.f;
    }
    __syncthreads();
    if (t < 32) {
        float acc = l1b[t];
#pragma unroll
        for (int k = 0; k < 70; ++k) acc += emb[k] * l1w[k * 32 + t];
        hid[t] = fmaxf(acc, 0.f);
    }
    __syncthreads();
    if (t < 2) {
        float acc = l2b[t];
#pragma unroll
        for (int j = 0; j < 32; ++j) acc += hid[j] * l2w[j * 2 + t];
        out[t] = 2.0f + 3.0f / (1.0f + expf(-acc));
    }
}

extern "C" void kernel_launch(void* const* d_in, const int* in_sizes, int n_in,
                              void* d_out, int out_size, void* d_ws, size_t ws_size,
                              hipStream_t stream) {
    const float* x   = (const float*)d_in[0];
    const int*   ei  = (const int*)d_in[1];
    const float* w1  = (const float*)d_in[2];
    const float* b1  = (const float*)d_in[3];
    const float* w2  = (const float*)d_in[4];
    const float* b2  = (const float*)d_in[5];
    const float* l1w = (const float*)d_in[6];
    const float* l1b = (const float*)d_in[7];
    const float* l2w = (const float*)d_in[8];
    const float* l2b = (const float*)d_in[9];

    const int n = in_sizes[0] / 5;
    const int E = in_sizes[1] / 2;
    const int* src = ei;
    const int* dst = ei + E;

    const int NBK = (n + BUCKET - 1) / BUCKET;   // 391 buckets
    const int NCH = NBK;                          // edge chunks
    const int chunk = (E + NCH - 1) / NCH;
    const int nb = NBK;                           // scan blocks (256/block)

    size_t nf = (size_t)n * 64;
    __hip_bfloat16* h1s = (__hip_bfloat16*)d_ws;      // N x 64 bf16 prescaled
    float* xs          = (float*)(h1s + nf);          // N x 8 (padded)
    float* agg5        = xs + (size_t)n * 8;          // N x 8 (padded)
    float* dinv        = agg5 + (size_t)n * 8;
    float* red         = dinv + n;                    // 96 floats
    int*   pos         = (int*)(red + 96);
    int*   rowend      = pos + n;
    int*   cursor      = rowend + n;
    int*   deg         = cursor + n;
    int*   bsum        = deg + n;                     // 512 ints
    int*   bucket_base = bsum + 512;                  // NBK+1
    int*   gcounts     = bucket_base + (MAXB + 8);    // NCH*NBK
    int*   records     = gcounts + NCH * NBK;         // E ints
    int*   ssrc        = records + E;                 // E ints, per-node CSR

    hipMemsetAsync(deg, 0, (size_t)n * sizeof(int), stream);

    k_deg<<<2048, 256, 0, stream>>>(dst, E, deg);
    k_hist<<<NCH, 512, 0, stream>>>(dst, E, chunk, gcounts, NBK);
    k_scanA<<<1, MAXB, 0, stream>>>(gcounts, bucket_base, red, NBK, NCH);
    k_scanB<<<NBK, MAXB, 0, stream>>>(gcounts, bucket_base, NBK, NCH);
    k_bucketize<<<NCH, 512, 0, stream>>>(src, dst, E, chunk, gcounts, records, NBK);

    k_blocksum<<<nb, 256, 0, stream>>>(deg, bsum, n);
    k_scanbsum<<<1, 512, 0, stream>>>(bsum, nb);
    k_scan2<<<nb, 256, 0, stream>>>(deg, bsum, x, pos, rowend, cursor, dinv, xs, red, n);

    dim3 sgrid(NBK, 8);
    k_scatter2<<<sgrid, 256, 0, stream>>>(records, bucket_base, cursor, ssrc);

    k_agg5<<<(n + 255) / 256, 256, 0, stream>>>(pos, rowend, ssrc, dinv, xs, agg5, n);
    k_h1<<<(int)((nf + 255) / 256), 256, 0, stream>>>(agg5, w1, b1, dinv, h1s, n);
    k_l2fuse<<<4096, 256, 0, stream>>>(pos, rowend, ssrc, dinv, h1s, w2, b2, red, n);

    k_head<<<1, 64, 0, stream>>>(red, l1w, l1b, l2w, l2b, (float*)d_out, n);
}

// Round 10
// 447.028 us; speedup vs baseline: 1.4288x; 1.4288x over previous
//
#include <hip/hip_runtime.h>
#include <hip/hip_bf16.h>
#include <math.h>

// ---------------------------------------------------------------------------
// GCN predictor: 2x GCNConv(relu) -> mean pool + global feats -> MLP head
// N=100K nodes, E=3.2M directed edges, H=64.
// R10: R7 pipeline restored (fused l2, per-bucket LDS CSR); k_csr widened to
// 1024 threads/block (16 waves) to fix its 13% occupancy latency bind.
// gf fused into k_csr epilogue; red zero-init fused into k_scanA.
// NO global atomics anywhere on the edge path (R1/R9 lesson: they write
// through to the fabric at ~100MB per 3.2M ops).
// ---------------------------------------------------------------------------

#define BUCKET 256
#define MAXB   512   // max buckets / max chunks (needs n <= 131072)
#define CSRT   1024  // k_csr block size

// per-chunk bucket histogram: gcounts[chunk*NBK + bucket]
__global__ void k_hist(const int* __restrict__ dst, int E, int chunk,
                       int* __restrict__ gcounts, int NBK) {
    __shared__ int lcnt[MAXB];
    for (int i = threadIdx.x; i < NBK; i += blockDim.x) lcnt[i] = 0;
    __syncthreads();
    int e0 = blockIdx.x * chunk;
    int e1 = min(e0 + chunk, E);
    for (int e = e0 + threadIdx.x; e < e1; e += blockDim.x)
        atomicAdd(&lcnt[dst[e] >> 8], 1);
    __syncthreads();
    for (int b = threadIdx.x; b < NBK; b += blockDim.x)
        gcounts[blockIdx.x * NBK + b] = lcnt[b];
}

// single block: bucket_base[b] = exclusive scan of per-bucket totals
// also zero-inits the red[] accumulator (saves a memset dispatch)
__global__ void k_scanA(const int* __restrict__ gcounts, int* __restrict__ bucket_base,
                        float* __restrict__ red, int NBK, int NCH) {
    __shared__ int lds[MAXB];
    int t = threadIdx.x;
    if (t < 96) red[t] = 0.f;
    int tot = 0;
    if (t < NBK)
        for (int c = 0; c < NCH; ++c) tot += gcounts[c * NBK + t];
    lds[t] = tot;
    __syncthreads();
    for (int off = 1; off < MAXB; off <<= 1) {
        int add = (t >= off) ? lds[t - off] : 0;
        __syncthreads();
        lds[t] += add;
        __syncthreads();
    }
    if (t < NBK) bucket_base[t] = lds[t] - tot;
    if (t == NBK - 1) bucket_base[NBK] = lds[t];
}

// per bucket: scan counts across chunks, in place:
// gcounts[c*NBK+b] becomes the global slot base for (chunk c, bucket b)
__global__ void k_scanB(int* __restrict__ gcounts, const int* __restrict__ bucket_base,
                        int NBK, int NCH) {
    __shared__ int lds[MAXB];
    int b = blockIdx.x;
    int t = threadIdx.x;
    int v = (t < NCH) ? gcounts[t * NBK + b] : 0;
    lds[t] = v;
    __syncthreads();
    for (int off = 1; off < MAXB; off <<= 1) {
        int add = (t >= off) ? lds[t - off] : 0;
        __syncthreads();
        lds[t] += add;
        __syncthreads();
    }
    if (t < NCH) gcounts[t * NBK + b] = bucket_base[b] + lds[t] - v;
}

// scatter packed records (local_d<<17 | src) into bucket-grouped order
__global__ void k_bucketize(const int* __restrict__ src, const int* __restrict__ dst,
                            int E, int chunk, const int* __restrict__ gcounts,
                            int* __restrict__ records, int NBK) {
    __shared__ int lcur[MAXB];
    for (int b = threadIdx.x; b < NBK; b += blockDim.x)
        lcur[b] = gcounts[blockIdx.x * NBK + b];
    __syncthreads();
    int e0 = blockIdx.x * chunk;
    int e1 = min(e0 + chunk, E);
    for (int e = e0 + threadIdx.x; e < e1; e += blockDim.x) {
        int d = dst[e];
        int b = d >> 8;
        int rec = ((d & 255) << 17) | src[e];
        int slot = atomicAdd(&lcur[b], 1);
        records[slot] = rec;
    }
}

// per-bucket CSR finalize (1024 threads = 16 waves for latency hiding):
// LDS histogram of local nodes -> scan -> pos/rowend/dinv/xs/gf epilogue ->
// scatter src into per-node-contiguous ssrc (writes stay in bucket region).
__global__ __launch_bounds__(CSRT)
void k_csr(const int* __restrict__ records, const int* __restrict__ bucket_base,
           const float* __restrict__ x,
           int* __restrict__ ssrc, int* __restrict__ pos, int* __restrict__ rowend,
           float* __restrict__ dinv, float* __restrict__ xs,
           float* __restrict__ red, int n) {
    __shared__ int cnt[BUCKET];
    __shared__ int lds[BUCKET];
    __shared__ int cursor[BUCKET];
    int t = threadIdx.x;
    int b = blockIdx.x;
    if (t < BUCKET) cnt[t] = 0;
    __syncthreads();
    int j0 = bucket_base[b], j1 = bucket_base[b + 1];
    for (int j = j0 + t; j < j1; j += CSRT)
        atomicAdd(&cnt[records[j] >> 17], 1);
    __syncthreads();
    int c = 0;
    if (t < BUCKET) { c = cnt[t]; lds[t] = c; }
    __syncthreads();
    for (int off = 1; off < BUCKET; off <<= 1) {
        int add = 0;
        if (t < BUCKET && t >= off) add = lds[t - off];
        __syncthreads();
        if (t < BUCKET) lds[t] += add;
        __syncthreads();
    }
    float s2 = 0.f, s3 = 0.f, s4 = 0.f, sm0 = 0.f, sm1 = 0.f, sc = 0.f;
    if (t < BUCKET) {
        int p = j0 + lds[t] - c;   // exclusive
        cursor[t] = p;
        int node = b * BUCKET + t;
        if (node < n) {
            pos[node] = p;
            rowend[node] = p + c;
            float d = rsqrtf((float)(c + 1));
            dinv[node] = d;
            float x0 = x[node * 5 + 0], x1 = x[node * 5 + 1], x2 = x[node * 5 + 2];
            float x3 = x[node * 5 + 3], x4 = x[node * 5 + 4];
            float4 o;
            o.x = x0 * d; o.y = x1 * d; o.z = x2 * d; o.w = x3 * d;
            ((float4*)xs)[node * 2] = o;
            xs[node * 8 + 4] = x4 * d;
            s2 = x2; s3 = x3; s4 = x4;
            if (x2 == 1.0f) { sm0 = x0; sm1 = x1; sc = 1.f; }
        }
    }
#pragma unroll
    for (int off = 32; off; off >>= 1) {
        s2 += __shfl_down(s2, off);
        s3 += __shfl_down(s3, off);
        s4 += __shfl_down(s4, off);
        sm0 += __shfl_down(sm0, off);
        sm1 += __shfl_down(sm1, off);
        sc += __shfl_down(sc, off);
    }
    if ((t & 63) == 0 && t < BUCKET) {
        atomicAdd(&red[64], s2);
        atomicAdd(&red[65], s3);
        atomicAdd(&red[66], s4);
        atomicAdd(&red[67], sm0);
        atomicAdd(&red[68], sm1);
        atomicAdd(&red[69], sc);
    }
    __syncthreads();
    for (int j = j0 + t; j < j1; j += CSRT) {
        int rec = records[j];
        int slot = atomicAdd(&cursor[rec >> 17], 1);
        ssrc[slot] = rec & 131071;
    }
}

// 5-dim aggregation: agg5[i,:] = dinv[i] * ( sum_{s in N(i)} xs[s,:] + xs[i,:] )
// thread per node; xs is ~3MB -> L2-resident gathers
__global__ void k_agg5(const int* __restrict__ pos, const int* __restrict__ rowend,
                       const int* __restrict__ ssrc, const float* __restrict__ dinv,
                       const float* __restrict__ xs, float* __restrict__ agg5, int n) {
    int i = blockIdx.x * blockDim.x + threadIdx.x;
    if (i >= n) return;
    const float4* xs4 = (const float4*)xs;
    float4 a = xs4[i * 2];            // self term
    float a4 = xs[i * 8 + 4];
    int beg = pos[i], end = rowend[i];
    int j = beg;
    for (; j + 1 < end; j += 2) {
        int s0 = ssrc[j], s1 = ssrc[j + 1];
        float4 v0 = xs4[s0 * 2]; float w0 = xs[s0 * 8 + 4];
        float4 v1 = xs4[s1 * 2]; float w1 = xs[s1 * 8 + 4];
        a.x += v0.x + v1.x; a.y += v0.y + v1.y;
        a.z += v0.z + v1.z; a.w += v0.w + v1.w;
        a4 += w0 + w1;
    }
    for (; j < end; ++j) {
        int s = ssrc[j];
        float4 v = xs4[s * 2];
        a.x += v.x; a.y += v.y; a.z += v.z; a.w += v.w;
        a4 += xs[s * 8 + 4];
    }
    float dd = dinv[i];
    float4 o; o.x = a.x * dd; o.y = a.y * dd; o.z = a.z * dd; o.w = a.w * dd;
    ((float4*)agg5)[i * 2] = o;
    agg5[i * 8 + 4] = a4 * dd;
}

// h1s[i,f] = bf16( dinv[i] * relu( agg5[i,:] @ W1[:,f] + b1[f] ) )  (wave/node)
__global__ void k_h1(const float* __restrict__ agg5, const float* __restrict__ W1,
                     const float* __restrict__ b1, const float* __restrict__ dinv,
                     __hip_bfloat16* __restrict__ h1s, int n) {
    int t = blockIdx.x * blockDim.x + threadIdx.x;
    int i = t >> 6, f = t & 63;
    if (i >= n) return;
    float a0 = agg5[i * 8 + 0], a1 = agg5[i * 8 + 1], a2 = agg5[i * 8 + 2];
    float a3 = agg5[i * 8 + 3], a4 = agg5[i * 8 + 4];
    float v = a0 * W1[f] + a1 * W1[64 + f] + a2 * W1[128 + f]
            + a3 * W1[192 + f] + a4 * W1[256 + f] + b1[f];
    h1s[(size_t)i * 64 + f] = __float2bfloat16(dinv[i] * fmaxf(v, 0.f));
}

// Layer 2 fully fused, 4 nodes per wave interleaved (R7 version):
// gather prescaled bf16 h1s rows for 4 independent neighbor streams (lockstep,
// predicated), then 4 interleaved shfl matmuls (@W2+b2+relu), mean-pool reduce.
__global__ __launch_bounds__(256)
void k_l2fuse(const int* __restrict__ pos, const int* __restrict__ rowend,
              const int* __restrict__ ssrc, const float* __restrict__ dinv,
              const __hip_bfloat16* __restrict__ h1s, const float* __restrict__ W2,
              const float* __restrict__ b2, float* __restrict__ red, int n) {
    __shared__ float red64[64];
    int t = threadIdx.x, f = t & 63;
    if (t < 64) red64[t] = 0.f;
    __syncthreads();
    int w = blockIdx.x * (blockDim.x >> 6) + (t >> 6);
    int nw = gridDim.x * (blockDim.x >> 6);
    float bf = b2[f];
    float psum = 0.f;
    int nt = (n + 3) >> 2;
    for (int task = w; task < nt; task += nw) {
        int i0 = task * 4, i1 = i0 + 1, i2 = i0 + 2, i3 = i0 + 3;
        bool v1 = i1 < n, v2 = i2 < n, v3 = i3 < n;
        int p0 = pos[i0],            e0 = rowend[i0];
        int p1 = v1 ? pos[i1] : 0,   e1 = v1 ? rowend[i1] : 0;
        int p2 = v2 ? pos[i2] : 0,   e2 = v2 ? rowend[i2] : 0;
        int p3 = v3 ? pos[i3] : 0,   e3 = v3 ? rowend[i3] : 0;
        float a0 = __bfloat162float(h1s[(size_t)i0 * 64 + f]);
        float a1 = v1 ? __bfloat162float(h1s[(size_t)i1 * 64 + f]) : 0.f;
        float a2 = v2 ? __bfloat162float(h1s[(size_t)i2 * 64 + f]) : 0.f;
        float a3 = v3 ? __bfloat162float(h1s[(size_t)i3 * 64 + f]) : 0.f;
        int len = max(max(e0 - p0, e1 - p1), max(e2 - p2, e3 - p3));
#pragma unroll 2
        for (int m = 0; m < len; ++m) {
            int j0 = p0 + m, j1 = p1 + m, j2 = p2 + m, j3 = p3 + m;
            int s0 = ssrc[j0 < e0 ? j0 : 0];
            int s1 = ssrc[j1 < e1 ? j1 : 0];
            int s2 = ssrc[j2 < e2 ? j2 : 0];
            int s3 = ssrc[j3 < e3 ? j3 : 0];
            float g0 = __bfloat162float(h1s[(size_t)s0 * 64 + f]);
            float g1 = __bfloat162float(h1s[(size_t)s1 * 64 + f]);
            float g2 = __bfloat162float(h1s[(size_t)s2 * 64 + f]);
            float g3 = __bfloat162float(h1s[(size_t)s3 * 64 + f]);
            if (j0 < e0) a0 += g0;
            if (j1 < e1) a1 += g1;
            if (j2 < e2) a2 += g2;
            if (j3 < e3) a3 += g3;
        }
        // conv2: out_k[f] = relu( dinv * sum_kk a_k[kk]*W2[kk,f] + b2[f] )
        float q0 = 0.f, q1 = 0.f, q2 = 0.f, q3 = 0.f;
#pragma unroll 8
        for (int k = 0; k < 64; ++k) {
            float w2v = W2[k * 64 + f];
            q0 += __shfl(a0, k) * w2v;
            q1 += __shfl(a1, k) * w2v;
            q2 += __shfl(a2, k) * w2v;
            q3 += __shfl(a3, k) * w2v;
        }
        psum += fmaxf(q0 * dinv[i0] + bf, 0.f);
        if (v1) psum += fmaxf(q1 * dinv[i1] + bf, 0.f);
        if (v2) psum += fmaxf(q2 * dinv[i2] + bf, 0.f);
        if (v3) psum += fmaxf(q3 * dinv[i3] + bf, 0.f);
    }
    atomicAdd(&red64[f], psum);
    __syncthreads();
    if (t < 64) atomicAdd(&red[t], red64[t]);
}

// Final head: emb = [mean(h2), gf(6)] (70), MLP 70->32->2, 2+3*sigmoid
__global__ void k_head(const float* __restrict__ red,
                       const float* __restrict__ l1w, const float* __restrict__ l1b,
                       const float* __restrict__ l2w, const float* __restrict__ l2b,
                       float* __restrict__ out, int n) {
    __shared__ float emb[70];
    __shared__ float hid[32];
    int t = threadIdx.x;
    if (t < 64) emb[t] = red[t] / (float)n;
    if (t == 0) {
        float n_comp = red[64], n_and = red[65], n_or = red[66];
        float cnt = red[69];
        float safe = fmaxf(cnt, 1.f);
        emb[64] = n_comp;
        emb[65] = n_and;
        emb[66] = n_or;
        emb[67] = n_and + n_or;
        emb[68] = cnt > 0.f ? red[67] / safe : 0.f;
        emb[69] = cnt > 0.f ? red[68] / safe : 0.f;
    }
    __syncthreads();
    if (t < 32) {
        float acc = l1b[t];
#pragma unroll
        for (int k = 0; k < 70; ++k) acc += emb[k] * l1w[k * 32 + t];
        hid[t] = fmaxf(acc, 0.f);
    }
    __syncthreads();
    if (t < 2) {
        float acc = l2b[t];
#pragma unroll
        for (int j = 0; j < 32; ++j) acc += hid[j] * l2w[j * 2 + t];
        out[t] = 2.0f + 3.0f / (1.0f + expf(-acc));
    }
}

extern "C" void kernel_launch(void* const* d_in, const int* in_sizes, int n_in,
                              void* d_out, int out_size, void* d_ws, size_t ws_size,
                              hipStream_t stream) {
    const float* x   = (const float*)d_in[0];
    const int*   ei  = (const int*)d_in[1];
    const float* w1  = (const float*)d_in[2];
    const float* b1  = (const float*)d_in[3];
    const float* w2  = (const float*)d_in[4];
    const float* b2  = (const float*)d_in[5];
    const float* l1w = (const float*)d_in[6];
    const float* l1b = (const float*)d_in[7];
    const float* l2w = (const float*)d_in[8];
    const float* l2b = (const float*)d_in[9];

    const int n = in_sizes[0] / 5;
    const int E = in_sizes[1] / 2;
    const int* src = ei;
    const int* dst = ei + E;

    const int NBK = (n + BUCKET - 1) / BUCKET;   // 391 buckets
    const int NCH = NBK;                          // edge chunks
    const int chunk = (E + NCH - 1) / NCH;

    size_t nf = (size_t)n * 64;
    __hip_bfloat16* h1s = (__hip_bfloat16*)d_ws;      // N x 64 bf16 prescaled
    float* xs          = (float*)(h1s + nf);          // N x 8 (padded)
    float* agg5        = xs + (size_t)n * 8;          // N x 8 (padded)
    float* dinv        = agg5 + (size_t)n * 8;
    float* red         = dinv + n;                    // 96 floats
    int*   pos         = (int*)(red + 96);
    int*   rowend      = pos + n;
    int*   bucket_base = rowend + n;                  // NBK+1
    int*   gcounts     = bucket_base + (MAXB + 8);    // NCH*NBK
    int*   records     = gcounts + NCH * NBK;         // E ints
    int*   ssrc        = records + E;                 // E ints, per-node CSR

    k_hist<<<NCH, 512, 0, stream>>>(dst, E, chunk, gcounts, NBK);
    k_scanA<<<1, MAXB, 0, stream>>>(gcounts, bucket_base, red, NBK, NCH);
    k_scanB<<<NBK, MAXB, 0, stream>>>(gcounts, bucket_base, NBK, NCH);
    k_bucketize<<<NCH, 512, 0, stream>>>(src, dst, E, chunk, gcounts, records, NBK);
    k_csr<<<NBK, CSRT, 0, stream>>>(records, bucket_base, x, ssrc, pos, rowend,
                                    dinv, xs, red, n);

    k_agg5<<<(n + 255) / 256, 256, 0, stream>>>(pos, rowend, ssrc, dinv, xs, agg5, n);
    k_h1<<<(int)((nf + 255) / 256), 256, 0, stream>>>(agg5, w1, b1, dinv, h1s, n);
    k_l2fuse<<<4096, 256, 0, stream>>>(pos, rowend, ssrc, dinv, h1s, w2, b2, red, n);

    k_head<<<1, 64, 0, stream>>>(red, l1w, l1b, l2w, l2b, (float*)d_out, n);
}

// Round 11
// 385.603 us; speedup vs baseline: 1.6565x; 1.1593x over previous
//
#include <hip/hip_runtime.h>
#include <hip/hip_bf16.h>
#include <math.h>

// ---------------------------------------------------------------------------
// GCN predictor: 2x GCNConv(relu) -> mean pool + global feats -> MLP head
// N=100K nodes, E=3.2M directed edges, H=64.
// R11: spread the LDS-atomic passes over many more blocks. Edge chunks
// 391->2048 (hist/bucketize); k_csr split into csrA (sliced histograms,
// 391x8 blocks), csrB (scan+epilogue), csrC (sliced scatter, 391x8).
// The LDS-atomic stream is throughput-bound (~4cyc/op/CU, R3/R10 evidence);
// only concurrency across CUs reduces wall time. l2fuse/agg5/h1 unchanged.
// ---------------------------------------------------------------------------

#define BUCKET 256
#define MAXB   512    // max buckets (needs n <= 131072)
#define NCHV   2048   // edge chunks
#define Q      8      // csr record slices per bucket

// per-chunk bucket histogram: gcounts[chunk*NBK + bucket]
__global__ void k_hist(const int* __restrict__ dst, int E, int chunk,
                       int* __restrict__ gcounts, int NBK) {
    __shared__ int lcnt[MAXB];
    for (int i = threadIdx.x; i < NBK; i += blockDim.x) lcnt[i] = 0;
    __syncthreads();
    int e0 = blockIdx.x * chunk;
    int e1 = min(e0 + chunk, E);
    for (int e = e0 + threadIdx.x; e < e1; e += blockDim.x)
        atomicAdd(&lcnt[dst[e] >> 8], 1);
    __syncthreads();
    for (int b = threadIdx.x; b < NBK; b += blockDim.x)
        gcounts[blockIdx.x * NBK + b] = lcnt[b];
}

// per-bucket totals: btot[b] = sum_c gcounts[c*NBK+b]
__global__ void k_colsum(const int* __restrict__ gcounts, int* __restrict__ btot,
                         int NBK, int NCH) {
    __shared__ int lds[256];
    int b = blockIdx.x, t = threadIdx.x;
    int s = 0;
    for (int c = t; c < NCH; c += 256) s += gcounts[c * NBK + b];
    lds[t] = s;
    __syncthreads();
    for (int off = 128; off; off >>= 1) {
        if (t < off) lds[t] += lds[t + off];
        __syncthreads();
    }
    if (t == 0) btot[b] = lds[0];
}

// single block: bucket_base = exclusive scan of btot; zero-init red
__global__ void k_scanA(const int* __restrict__ btot, int* __restrict__ bucket_base,
                        float* __restrict__ red, int NBK) {
    __shared__ int lds[MAXB];
    int t = threadIdx.x;
    if (t < 96) red[t] = 0.f;
    int v = (t < NBK) ? btot[t] : 0;
    lds[t] = v;
    __syncthreads();
    for (int off = 1; off < MAXB; off <<= 1) {
        int add = (t >= off) ? lds[t - off] : 0;
        __syncthreads();
        lds[t] += add;
        __syncthreads();
    }
    if (t < NBK) bucket_base[t] = lds[t] - v;
    if (t == NBK - 1) bucket_base[NBK] = lds[t];
}

// per bucket: exclusive scan of gcounts[c*NBK+b] over c (NCH entries, 4 rounds
// of 512 with carry), in place -> per-(chunk,bucket) slot bases
__global__ void k_scanB(int* __restrict__ gcounts, const int* __restrict__ bucket_base,
                        int NBK, int NCH) {
    __shared__ int lds[512];
    int b = blockIdx.x, t = threadIdx.x;
    int carry = bucket_base[b];
    for (int base = 0; base < NCH; base += 512) {
        int c = base + t;
        int v = (c < NCH) ? gcounts[c * NBK + b] : 0;
        lds[t] = v;
        __syncthreads();
        for (int off = 1; off < 512; off <<= 1) {
            int add = (t >= off) ? lds[t - off] : 0;
            __syncthreads();
            lds[t] += add;
            __syncthreads();
        }
        if (c < NCH) gcounts[c * NBK + b] = carry + lds[t] - v;
        int tot = lds[511];
        __syncthreads();
        carry += tot;
    }
}

// scatter packed records (local_d<<17 | src) into bucket-grouped order
__global__ void k_bucketize(const int* __restrict__ src, const int* __restrict__ dst,
                            int E, int chunk, const int* __restrict__ gcounts,
                            int* __restrict__ records, int NBK) {
    __shared__ int lcur[MAXB];
    for (int b = threadIdx.x; b < NBK; b += blockDim.x)
        lcur[b] = gcounts[blockIdx.x * NBK + b];
    __syncthreads();
    int e0 = blockIdx.x * chunk;
    int e1 = min(e0 + chunk, E);
    for (int e = e0 + threadIdx.x; e < e1; e += blockDim.x) {
        int d = dst[e];
        int b = d >> 8;
        int rec = ((d & 255) << 17) | src[e];
        int slot = atomicAdd(&lcur[b], 1);
        records[slot] = rec;
    }
}

// csrA: per-(bucket, slice) histogram of local nodes -> qhist
__global__ void k_csrA(const int* __restrict__ records, const int* __restrict__ bucket_base,
                       int* __restrict__ qhist) {
    __shared__ int cnt[BUCKET];
    int t = threadIdx.x, b = blockIdx.x, q = blockIdx.y;
    if (t < BUCKET) cnt[t] = 0;
    __syncthreads();
    int j0 = bucket_base[b], j1 = bucket_base[b + 1];
    int qlen = (j1 - j0 + Q - 1) / Q;
    int qs = j0 + q * qlen;
    int qe = min(qs + qlen, j1);
    for (int j = qs + t; j < qe; j += blockDim.x)
        atomicAdd(&cnt[records[j] >> 17], 1);
    __syncthreads();
    if (t < BUCKET) qhist[(b * Q + q) * BUCKET + t] = cnt[t];
}

// csrB: per-bucket scan of summed slice histograms -> pos/rowend/dinv/xs/gf,
// and per-slice cursor bases qbase
__global__ void k_csrB(const int* __restrict__ qhist, const int* __restrict__ bucket_base,
                       const float* __restrict__ x,
                       int* __restrict__ qbase, int* __restrict__ pos,
                       int* __restrict__ rowend, float* __restrict__ dinv,
                       float* __restrict__ xs, float* __restrict__ red, int n) {
    __shared__ int lds[BUCKET];
    int t = threadIdx.x, b = blockIdx.x;
    int h[Q];
    int c = 0;
#pragma unroll
    for (int q = 0; q < Q; ++q) {
        h[q] = qhist[(b * Q + q) * BUCKET + t];
        c += h[q];
    }
    lds[t] = c;
    __syncthreads();
    for (int off = 1; off < BUCKET; off <<= 1) {
        int add = (t >= off) ? lds[t - off] : 0;
        __syncthreads();
        lds[t] += add;
        __syncthreads();
    }
    int j0 = bucket_base[b];
    int p = j0 + lds[t] - c;   // exclusive: row start for node (b,t)
    int run = p;
#pragma unroll
    for (int q = 0; q < Q; ++q) {
        qbase[(b * Q + q) * BUCKET + t] = run;
        run += h[q];
    }
    int node = b * BUCKET + t;
    float s2 = 0.f, s3 = 0.f, s4 = 0.f, sm0 = 0.f, sm1 = 0.f, sc = 0.f;
    if (node < n) {
        pos[node] = p;
        rowend[node] = p + c;
        float d = rsqrtf((float)(c + 1));
        dinv[node] = d;
        float x0 = x[node * 5 + 0], x1 = x[node * 5 + 1], x2 = x[node * 5 + 2];
        float x3 = x[node * 5 + 3], x4 = x[node * 5 + 4];
        float4 o;
        o.x = x0 * d; o.y = x1 * d; o.z = x2 * d; o.w = x3 * d;
        ((float4*)xs)[node * 2] = o;
        xs[node * 8 + 4] = x4 * d;
        s2 = x2; s3 = x3; s4 = x4;
        if (x2 == 1.0f) { sm0 = x0; sm1 = x1; sc = 1.f; }
    }
#pragma unroll
    for (int off = 32; off; off >>= 1) {
        s2 += __shfl_down(s2, off);
        s3 += __shfl_down(s3, off);
        s4 += __shfl_down(s4, off);
        sm0 += __shfl_down(sm0, off);
        sm1 += __shfl_down(sm1, off);
        sc += __shfl_down(sc, off);
    }
    if ((t & 63) == 0) {
        atomicAdd(&red[64], s2);
        atomicAdd(&red[65], s3);
        atomicAdd(&red[66], s4);
        atomicAdd(&red[67], sm0);
        atomicAdd(&red[68], sm1);
        atomicAdd(&red[69], sc);
    }
}

// csrC: per-(bucket, slice) scatter into per-node CSR using private cursors
__global__ void k_csrC(const int* __restrict__ records, const int* __restrict__ bucket_base,
                       const int* __restrict__ qbase, int* __restrict__ ssrc) {
    __shared__ int cursor[BUCKET];
    int t = threadIdx.x, b = blockIdx.x, q = blockIdx.y;
    if (t < BUCKET) cursor[t] = qbase[(b * Q + q) * BUCKET + t];
    __syncthreads();
    int j0 = bucket_base[b], j1 = bucket_base[b + 1];
    int qlen = (j1 - j0 + Q - 1) / Q;
    int qs = j0 + q * qlen;
    int qe = min(qs + qlen, j1);
    for (int j = qs + t; j < qe; j += blockDim.x) {
        int rec = records[j];
        int slot = atomicAdd(&cursor[rec >> 17], 1);
        ssrc[slot] = rec & 131071;
    }
}

// 5-dim aggregation: agg5[i,:] = dinv[i] * ( sum_{s in N(i)} xs[s,:] + xs[i,:] )
__global__ void k_agg5(const int* __restrict__ pos, const int* __restrict__ rowend,
                       const int* __restrict__ ssrc, const float* __restrict__ dinv,
                       const float* __restrict__ xs, float* __restrict__ agg5, int n) {
    int i = blockIdx.x * blockDim.x + threadIdx.x;
    if (i >= n) return;
    const float4* xs4 = (const float4*)xs;
    float4 a = xs4[i * 2];            // self term
    float a4 = xs[i * 8 + 4];
    int beg = pos[i], end = rowend[i];
    int j = beg;
    for (; j + 1 < end; j += 2) {
        int s0 = ssrc[j], s1 = ssrc[j + 1];
        float4 v0 = xs4[s0 * 2]; float w0 = xs[s0 * 8 + 4];
        float4 v1 = xs4[s1 * 2]; float w1 = xs[s1 * 8 + 4];
        a.x += v0.x + v1.x; a.y += v0.y + v1.y;
        a.z += v0.z + v1.z; a.w += v0.w + v1.w;
        a4 += w0 + w1;
    }
    for (; j < end; ++j) {
        int s = ssrc[j];
        float4 v = xs4[s * 2];
        a.x += v.x; a.y += v.y; a.z += v.z; a.w += v.w;
        a4 += xs[s * 8 + 4];
    }
    float dd = dinv[i];
    float4 o; o.x = a.x * dd; o.y = a.y * dd; o.z = a.z * dd; o.w = a.w * dd;
    ((float4*)agg5)[i * 2] = o;
    agg5[i * 8 + 4] = a4 * dd;
}

// h1s[i,f] = bf16( dinv[i] * relu( agg5[i,:] @ W1[:,f] + b1[f] ) )  (wave/node)
__global__ void k_h1(const float* __restrict__ agg5, const float* __restrict__ W1,
                     const float* __restrict__ b1, const float* __restrict__ dinv,
                     __hip_bfloat16* __restrict__ h1s, int n) {
    int t = blockIdx.x * blockDim.x + threadIdx.x;
    int i = t >> 6, f = t & 63;
    if (i >= n) return;
    float a0 = agg5[i * 8 + 0], a1 = agg5[i * 8 + 1], a2 = agg5[i * 8 + 2];
    float a3 = agg5[i * 8 + 3], a4 = agg5[i * 8 + 4];
    float v = a0 * W1[f] + a1 * W1[64 + f] + a2 * W1[128 + f]
            + a3 * W1[192 + f] + a4 * W1[256 + f] + b1[f];
    h1s[(size_t)i * 64 + f] = __float2bfloat16(dinv[i] * fmaxf(v, 0.f));
}

// Layer 2 fully fused, 4 nodes per wave interleaved (R7 version)
__global__ __launch_bounds__(256)
void k_l2fuse(const int* __restrict__ pos, const int* __restrict__ rowend,
              const int* __restrict__ ssrc, const float* __restrict__ dinv,
              const __hip_bfloat16* __restrict__ h1s, const float* __restrict__ W2,
              const float* __restrict__ b2, float* __restrict__ red, int n) {
    __shared__ float red64[64];
    int t = threadIdx.x, f = t & 63;
    if (t < 64) red64[t] = 0.f;
    __syncthreads();
    int w = blockIdx.x * (blockDim.x >> 6) + (t >> 6);
    int nw = gridDim.x * (blockDim.x >> 6);
    float bf = b2[f];
    float psum = 0.f;
    int nt = (n + 3) >> 2;
    for (int task = w; task < nt; task += nw) {
        int i0 = task * 4, i1 = i0 + 1, i2 = i0 + 2, i3 = i0 + 3;
        bool v1 = i1 < n, v2 = i2 < n, v3 = i3 < n;
        int p0 = pos[i0],            e0 = rowend[i0];
        int p1 = v1 ? pos[i1] : 0,   e1 = v1 ? rowend[i1] : 0;
        int p2 = v2 ? pos[i2] : 0,   e2 = v2 ? rowend[i2] : 0;
        int p3 = v3 ? pos[i3] : 0,   e3 = v3 ? rowend[i3] : 0;
        float a0 = __bfloat162float(h1s[(size_t)i0 * 64 + f]);
        float a1 = v1 ? __bfloat162float(h1s[(size_t)i1 * 64 + f]) : 0.f;
        float a2 = v2 ? __bfloat162float(h1s[(size_t)i2 * 64 + f]) : 0.f;
        float a3 = v3 ? __bfloat162float(h1s[(size_t)i3 * 64 + f]) : 0.f;
        int len = max(max(e0 - p0, e1 - p1), max(e2 - p2, e3 - p3));
#pragma unroll 2
        for (int m = 0; m < len; ++m) {
            int j0 = p0 + m, j1 = p1 + m, j2 = p2 + m, j3 = p3 + m;
            int s0 = ssrc[j0 < e0 ? j0 : 0];
            int s1 = ssrc[j1 < e1 ? j1 : 0];
            int s2 = ssrc[j2 < e2 ? j2 : 0];
            int s3 = ssrc[j3 < e3 ? j3 : 0];
            float g0 = __bfloat162float(h1s[(size_t)s0 * 64 + f]);
            float g1 = __bfloat162float(h1s[(size_t)s1 * 64 + f]);
            float g2 = __bfloat162float(h1s[(size_t)s2 * 64 + f]);
            float g3 = __bfloat162float(h1s[(size_t)s3 * 64 + f]);
            if (j0 < e0) a0 += g0;
            if (j1 < e1) a1 += g1;
            if (j2 < e2) a2 += g2;
            if (j3 < e3) a3 += g3;
        }
        float q0 = 0.f, q1 = 0.f, q2 = 0.f, q3 = 0.f;
#pragma unroll 8
        for (int k = 0; k < 64; ++k) {
            float w2v = W2[k * 64 + f];
            q0 += __shfl(a0, k) * w2v;
            q1 += __shfl(a1, k) * w2v;
            q2 += __shfl(a2, k) * w2v;
            q3 += __shfl(a3, k) * w2v;
        }
        psum += fmaxf(q0 * dinv[i0] + bf, 0.f);
        if (v1) psum += fmaxf(q1 * dinv[i1] + bf, 0.f);
        if (v2) psum += fmaxf(q2 * dinv[i2] + bf, 0.f);
        if (v3) psum += fmaxf(q3 * dinv[i3] + bf, 0.f);
    }
    atomicAdd(&red64[f], psum);
    __syncthreads();
    if (t < 64) atomicAdd(&red[t], red64[t]);
}

// Final head: emb = [mean(h2), gf(6)] (70), MLP 70->32->2, 2+3*sigmoid
__global__ void k_head(const float* __restrict__ red,
                       const float* __restrict__ l1w, const float* __restrict__ l1b,
                       const float* __restrict__ l2w, const float* __restrict__ l2b,
                       float* __restrict__ out, int n) {
    __shared__ float emb[70];
    __shared__ float hid[32];
    int t = threadIdx.x;
    if (t < 64) emb[t] = red[t] / (float)n;
    if (t == 0) {
        float n_comp = red[64], n_and = red[65], n_or = red[66];
        float cnt = red[69];
        float safe = fmaxf(cnt, 1.f);
        emb[64] = n_comp;
        emb[65] = n_and;
        emb[66] = n_or;
        emb[67] = n_and + n_or;
        emb[68] = cnt > 0.f ? red[67] / safe : 0.f;
        emb[69] = cnt > 0.f ? red[68] / safe : 0.f;
    }
    __syncthreads();
    if (t < 32) {
        float acc = l1b[t];
#pragma unroll
        for (int k = 0; k < 70; ++k) acc += emb[k] * l1w[k * 32 + t];
        hid[t] = fmaxf(acc, 0.f);
    }
    __syncthreads();
    if (t < 2) {
        float acc = l2b[t];
#pragma unroll
        for (int j = 0; j < 32; ++j) acc += hid[j] * l2w[j * 2 + t];
        out[t] = 2.0f + 3.0f / (1.0f + expf(-acc));
    }
}

extern "C" void kernel_launch(void* const* d_in, const int* in_sizes, int n_in,
                              void* d_out, int out_size, void* d_ws, size_t ws_size,
                              hipStream_t stream) {
    const float* x   = (const float*)d_in[0];
    const int*   ei  = (const int*)d_in[1];
    const float* w1  = (const float*)d_in[2];
    const float* b1  = (const float*)d_in[3];
    const float* w2  = (const float*)d_in[4];
    const float* b2  = (const float*)d_in[5];
    const float* l1w = (const float*)d_in[6];
    const float* l1b = (const float*)d_in[7];
    const float* l2w = (const float*)d_in[8];
    const float* l2b = (const float*)d_in[9];

    const int n = in_sizes[0] / 5;
    const int E = in_sizes[1] / 2;
    const int* src = ei;
    const int* dst = ei + E;

    const int NBK = (n + BUCKET - 1) / BUCKET;   // 391 buckets
    const int NCH = NCHV;                         // 2048 edge chunks
    const int chunk = (E + NCH - 1) / NCH;

    size_t nf = (size_t)n * 64;
    __hip_bfloat16* h1s = (__hip_bfloat16*)d_ws;      // N x 64 bf16 prescaled
    float* xs          = (float*)(h1s + nf);          // N x 8 (padded)
    float* agg5        = xs + (size_t)n * 8;          // N x 8 (padded)
    float* dinv        = agg5 + (size_t)n * 8;
    float* red         = dinv + n;                    // 96 floats
    int*   pos         = (int*)(red + 96);
    int*   rowend      = pos + n;
    int*   btot        = rowend + n;                  // MAXB ints
    int*   bucket_base = btot + MAXB;                 // NBK+1
    int*   qhist       = bucket_base + (MAXB + 8);    // NBK*Q*256
    int*   qbase       = qhist + NBK * Q * BUCKET;    // NBK*Q*256
    int*   gcounts     = qbase + NBK * Q * BUCKET;    // NCH*NBK
    int*   records     = gcounts + NCH * NBK;         // E ints
    int*   ssrc        = records + E;                 // E ints, per-node CSR

    k_hist<<<NCH, 512, 0, stream>>>(dst, E, chunk, gcounts, NBK);
    k_colsum<<<NBK, 256, 0, stream>>>(gcounts, btot, NBK, NCH);
    k_scanA<<<1, MAXB, 0, stream>>>(btot, bucket_base, red, NBK);
    k_scanB<<<NBK, 512, 0, stream>>>(gcounts, bucket_base, NBK, NCH);
    k_bucketize<<<NCH, 512, 0, stream>>>(src, dst, E, chunk, gcounts, records, NBK);

    dim3 qgrid(NBK, Q);
    k_csrA<<<qgrid, 512, 0, stream>>>(records, bucket_base, qhist);
    k_csrB<<<NBK, BUCKET, 0, stream>>>(qhist, bucket_base, x, qbase, pos, rowend,
                                       dinv, xs, red, n);
    k_csrC<<<qgrid, 512, 0, stream>>>(records, bucket_base, qbase, ssrc);

    k_agg5<<<(n + 255) / 256, 256, 0, stream>>>(pos, rowend, ssrc, dinv, xs, agg5, n);
    k_h1<<<(int)((nf + 255) / 256), 256, 0, stream>>>(agg5, w1, b1, dinv, h1s, n);
    k_l2fuse<<<4096, 256, 0, stream>>>(pos, rowend, ssrc, dinv, h1s, w2, b2, red, n);

    k_head<<<1, 64, 0, stream>>>(red, l1w, l1b, l2w, l2b, (float*)d_out, n);
}

// Round 12
// 264.994 us; speedup vs baseline: 2.4104x; 1.4551x over previous
//
#include <hip/hip_runtime.h>
#include <hip/hip_bf16.h>
#include <math.h>

// ---------------------------------------------------------------------------
// GCN predictor: 2x GCNConv(relu) -> mean pool + global feats -> MLP head
// N=100K nodes, E=3.2M directed edges, H=64.
// R12: eliminate hot-address device atomics (measured ~80ns/op serialized:
// csrB spent 124us on 9384 atomics to 6 addresses). gf -> per-block partials
// + reduce in k_head; l2fuse final accumulation spread over 32 copies of the
// 64-wide accumulator. Everything else = R11.
// ---------------------------------------------------------------------------

#define BUCKET 256
#define MAXB   512    // max buckets (needs n <= 131072)
#define NCHV   2048   // edge chunks
#define Q      8      // csr record slices per bucket
#define RCOPY  32     // spread copies for the mean-pool accumulator

// per-chunk bucket histogram: gcounts[chunk*NBK + bucket]
__global__ void k_hist(const int* __restrict__ dst, int E, int chunk,
                       int* __restrict__ gcounts, int NBK) {
    __shared__ int lcnt[MAXB];
    for (int i = threadIdx.x; i < NBK; i += blockDim.x) lcnt[i] = 0;
    __syncthreads();
    int e0 = blockIdx.x * chunk;
    int e1 = min(e0 + chunk, E);
    for (int e = e0 + threadIdx.x; e < e1; e += blockDim.x)
        atomicAdd(&lcnt[dst[e] >> 8], 1);
    __syncthreads();
    for (int b = threadIdx.x; b < NBK; b += blockDim.x)
        gcounts[blockIdx.x * NBK + b] = lcnt[b];
}

// per-bucket totals: btot[b] = sum_c gcounts[c*NBK+b]
__global__ void k_colsum(const int* __restrict__ gcounts, int* __restrict__ btot,
                         int NBK, int NCH) {
    __shared__ int lds[256];
    int b = blockIdx.x, t = threadIdx.x;
    int s = 0;
    for (int c = t; c < NCH; c += 256) s += gcounts[c * NBK + b];
    lds[t] = s;
    __syncthreads();
    for (int off = 128; off; off >>= 1) {
        if (t < off) lds[t] += lds[t + off];
        __syncthreads();
    }
    if (t == 0) btot[b] = lds[0];
}

// single block: bucket_base = exclusive scan of btot; zero-init red copies
__global__ void k_scanA(const int* __restrict__ btot, int* __restrict__ bucket_base,
                        float* __restrict__ red, int NBK) {
    __shared__ int lds[MAXB];
    int t = threadIdx.x;
    for (int i = t; i < RCOPY * 64; i += MAXB) red[i] = 0.f;
    int v = (t < NBK) ? btot[t] : 0;
    lds[t] = v;
    __syncthreads();
    for (int off = 1; off < MAXB; off <<= 1) {
        int add = (t >= off) ? lds[t - off] : 0;
        __syncthreads();
        lds[t] += add;
        __syncthreads();
    }
    if (t < NBK) bucket_base[t] = lds[t] - v;
    if (t == NBK - 1) bucket_base[NBK] = lds[t];
}

// per bucket: exclusive scan of gcounts[c*NBK+b] over c, in place
__global__ void k_scanB(int* __restrict__ gcounts, const int* __restrict__ bucket_base,
                        int NBK, int NCH) {
    __shared__ int lds[512];
    int b = blockIdx.x, t = threadIdx.x;
    int carry = bucket_base[b];
    for (int base = 0; base < NCH; base += 512) {
        int c = base + t;
        int v = (c < NCH) ? gcounts[c * NBK + b] : 0;
        lds[t] = v;
        __syncthreads();
        for (int off = 1; off < 512; off <<= 1) {
            int add = (t >= off) ? lds[t - off] : 0;
            __syncthreads();
            lds[t] += add;
            __syncthreads();
        }
        if (c < NCH) gcounts[c * NBK + b] = carry + lds[t] - v;
        int tot = lds[511];
        __syncthreads();
        carry += tot;
    }
}

// scatter packed records (local_d<<17 | src) into bucket-grouped order
__global__ void k_bucketize(const int* __restrict__ src, const int* __restrict__ dst,
                            int E, int chunk, const int* __restrict__ gcounts,
                            int* __restrict__ records, int NBK) {
    __shared__ int lcur[MAXB];
    for (int b = threadIdx.x; b < NBK; b += blockDim.x)
        lcur[b] = gcounts[blockIdx.x * NBK + b];
    __syncthreads();
    int e0 = blockIdx.x * chunk;
    int e1 = min(e0 + chunk, E);
    for (int e = e0 + threadIdx.x; e < e1; e += blockDim.x) {
        int d = dst[e];
        int b = d >> 8;
        int rec = ((d & 255) << 17) | src[e];
        int slot = atomicAdd(&lcur[b], 1);
        records[slot] = rec;
    }
}

// csrA: per-(bucket, slice) histogram of local nodes -> qhist
__global__ void k_csrA(const int* __restrict__ records, const int* __restrict__ bucket_base,
                       int* __restrict__ qhist) {
    __shared__ int cnt[BUCKET];
    int t = threadIdx.x, b = blockIdx.x, q = blockIdx.y;
    if (t < BUCKET) cnt[t] = 0;
    __syncthreads();
    int j0 = bucket_base[b], j1 = bucket_base[b + 1];
    int qlen = (j1 - j0 + Q - 1) / Q;
    int qs = j0 + q * qlen;
    int qe = min(qs + qlen, j1);
    for (int j = qs + t; j < qe; j += blockDim.x)
        atomicAdd(&cnt[records[j] >> 17], 1);
    __syncthreads();
    if (t < BUCKET) qhist[(b * Q + q) * BUCKET + t] = cnt[t];
}

// csrB: per-bucket scan of summed slice histograms -> pos/rowend/dinv/xs,
// per-slice cursor bases qbase, and per-block gf partials (NO hot atomics)
__global__ void k_csrB(const int* __restrict__ qhist, const int* __restrict__ bucket_base,
                       const float* __restrict__ x,
                       int* __restrict__ qbase, int* __restrict__ pos,
                       int* __restrict__ rowend, float* __restrict__ dinv,
                       float* __restrict__ xs, float* __restrict__ gfpart, int n) {
    __shared__ int lds[BUCKET];
    __shared__ float gf6[8];
    int t = threadIdx.x, b = blockIdx.x;
    if (t < 8) gf6[t] = 0.f;
    int h[Q];
    int c = 0;
#pragma unroll
    for (int q = 0; q < Q; ++q) {
        h[q] = qhist[(b * Q + q) * BUCKET + t];
        c += h[q];
    }
    lds[t] = c;
    __syncthreads();
    for (int off = 1; off < BUCKET; off <<= 1) {
        int add = (t >= off) ? lds[t - off] : 0;
        __syncthreads();
        lds[t] += add;
        __syncthreads();
    }
    int j0 = bucket_base[b];
    int p = j0 + lds[t] - c;   // exclusive: row start for node (b,t)
    int run = p;
#pragma unroll
    for (int q = 0; q < Q; ++q) {
        qbase[(b * Q + q) * BUCKET + t] = run;
        run += h[q];
    }
    int node = b * BUCKET + t;
    float s2 = 0.f, s3 = 0.f, s4 = 0.f, sm0 = 0.f, sm1 = 0.f, sc = 0.f;
    if (node < n) {
        pos[node] = p;
        rowend[node] = p + c;
        float d = rsqrtf((float)(c + 1));
        dinv[node] = d;
        float x0 = x[node * 5 + 0], x1 = x[node * 5 + 1], x2 = x[node * 5 + 2];
        float x3 = x[node * 5 + 3], x4 = x[node * 5 + 4];
        float4 o;
        o.x = x0 * d; o.y = x1 * d; o.z = x2 * d; o.w = x3 * d;
        ((float4*)xs)[node * 2] = o;
        xs[node * 8 + 4] = x4 * d;
        s2 = x2; s3 = x3; s4 = x4;
        if (x2 == 1.0f) { sm0 = x0; sm1 = x1; sc = 1.f; }
    }
#pragma unroll
    for (int off = 32; off; off >>= 1) {
        s2 += __shfl_down(s2, off);
        s3 += __shfl_down(s3, off);
        s4 += __shfl_down(s4, off);
        sm0 += __shfl_down(sm0, off);
        sm1 += __shfl_down(sm1, off);
        sc += __shfl_down(sc, off);
    }
    if ((t & 63) == 0) {            // 4 waves -> LDS accumulate (cheap)
        atomicAdd(&gf6[0], s2);
        atomicAdd(&gf6[1], s3);
        atomicAdd(&gf6[2], s4);
        atomicAdd(&gf6[3], sm0);
        atomicAdd(&gf6[4], sm1);
        atomicAdd(&gf6[5], sc);
    }
    __syncthreads();
    if (t < 6) gfpart[b * 8 + t] = gf6[t];
}

// csrC: per-(bucket, slice) scatter into per-node CSR using private cursors
__global__ void k_csrC(const int* __restrict__ records, const int* __restrict__ bucket_base,
                       const int* __restrict__ qbase, int* __restrict__ ssrc) {
    __shared__ int cursor[BUCKET];
    int t = threadIdx.x, b = blockIdx.x, q = blockIdx.y;
    if (t < BUCKET) cursor[t] = qbase[(b * Q + q) * BUCKET + t];
    __syncthreads();
    int j0 = bucket_base[b], j1 = bucket_base[b + 1];
    int qlen = (j1 - j0 + Q - 1) / Q;
    int qs = j0 + q * qlen;
    int qe = min(qs + qlen, j1);
    for (int j = qs + t; j < qe; j += blockDim.x) {
        int rec = records[j];
        int slot = atomicAdd(&cursor[rec >> 17], 1);
        ssrc[slot] = rec & 131071;
    }
}

// 5-dim aggregation: agg5[i,:] = dinv[i] * ( sum_{s in N(i)} xs[s,:] + xs[i,:] )
__global__ void k_agg5(const int* __restrict__ pos, const int* __restrict__ rowend,
                       const int* __restrict__ ssrc, const float* __restrict__ dinv,
                       const float* __restrict__ xs, float* __restrict__ agg5, int n) {
    int i = blockIdx.x * blockDim.x + threadIdx.x;
    if (i >= n) return;
    const float4* xs4 = (const float4*)xs;
    float4 a = xs4[i * 2];            // self term
    float a4 = xs[i * 8 + 4];
    int beg = pos[i], end = rowend[i];
    int j = beg;
    for (; j + 1 < end; j += 2) {
        int s0 = ssrc[j], s1 = ssrc[j + 1];
        float4 v0 = xs4[s0 * 2]; float w0 = xs[s0 * 8 + 4];
        float4 v1 = xs4[s1 * 2]; float w1 = xs[s1 * 8 + 4];
        a.x += v0.x + v1.x; a.y += v0.y + v1.y;
        a.z += v0.z + v1.z; a.w += v0.w + v1.w;
        a4 += w0 + w1;
    }
    for (; j < end; ++j) {
        int s = ssrc[j];
        float4 v = xs4[s * 2];
        a.x += v.x; a.y += v.y; a.z += v.z; a.w += v.w;
        a4 += xs[s * 8 + 4];
    }
    float dd = dinv[i];
    float4 o; o.x = a.x * dd; o.y = a.y * dd; o.z = a.z * dd; o.w = a.w * dd;
    ((float4*)agg5)[i * 2] = o;
    agg5[i * 8 + 4] = a4 * dd;
}

// h1s[i,f] = bf16( dinv[i] * relu( agg5[i,:] @ W1[:,f] + b1[f] ) )  (wave/node)
__global__ void k_h1(const float* __restrict__ agg5, const float* __restrict__ W1,
                     const float* __restrict__ b1, const float* __restrict__ dinv,
                     __hip_bfloat16* __restrict__ h1s, int n) {
    int t = blockIdx.x * blockDim.x + threadIdx.x;
    int i = t >> 6, f = t & 63;
    if (i >= n) return;
    float a0 = agg5[i * 8 + 0], a1 = agg5[i * 8 + 1], a2 = agg5[i * 8 + 2];
    float a3 = agg5[i * 8 + 3], a4 = agg5[i * 8 + 4];
    float v = a0 * W1[f] + a1 * W1[64 + f] + a2 * W1[128 + f]
            + a3 * W1[192 + f] + a4 * W1[256 + f] + b1[f];
    h1s[(size_t)i * 64 + f] = __float2bfloat16(dinv[i] * fmaxf(v, 0.f));
}

// Layer 2 fully fused, 4 nodes per wave interleaved; final accumulation
// spread over RCOPY copies of the 64-wide accumulator (atomic decongestion)
__global__ __launch_bounds__(256)
void k_l2fuse(const int* __restrict__ pos, const int* __restrict__ rowend,
              const int* __restrict__ ssrc, const float* __restrict__ dinv,
              const __hip_bfloat16* __restrict__ h1s, const float* __restrict__ W2,
              const float* __restrict__ b2, float* __restrict__ red, int n) {
    __shared__ float red64[64];
    int t = threadIdx.x, f = t & 63;
    if (t < 64) red64[t] = 0.f;
    __syncthreads();
    int w = blockIdx.x * (blockDim.x >> 6) + (t >> 6);
    int nw = gridDim.x * (blockDim.x >> 6);
    float bf = b2[f];
    float psum = 0.f;
    int nt = (n + 3) >> 2;
    for (int task = w; task < nt; task += nw) {
        int i0 = task * 4, i1 = i0 + 1, i2 = i0 + 2, i3 = i0 + 3;
        bool v1 = i1 < n, v2 = i2 < n, v3 = i3 < n;
        int p0 = pos[i0],            e0 = rowend[i0];
        int p1 = v1 ? pos[i1] : 0,   e1 = v1 ? rowend[i1] : 0;
        int p2 = v2 ? pos[i2] : 0,   e2 = v2 ? rowend[i2] : 0;
        int p3 = v3 ? pos[i3] : 0,   e3 = v3 ? rowend[i3] : 0;
        float a0 = __bfloat162float(h1s[(size_t)i0 * 64 + f]);
        float a1 = v1 ? __bfloat162float(h1s[(size_t)i1 * 64 + f]) : 0.f;
        float a2 = v2 ? __bfloat162float(h1s[(size_t)i2 * 64 + f]) : 0.f;
        float a3 = v3 ? __bfloat162float(h1s[(size_t)i3 * 64 + f]) : 0.f;
        int len = max(max(e0 - p0, e1 - p1), max(e2 - p2, e3 - p3));
#pragma unroll 2
        for (int m = 0; m < len; ++m) {
            int j0 = p0 + m, j1 = p1 + m, j2 = p2 + m, j3 = p3 + m;
            int s0 = ssrc[j0 < e0 ? j0 : 0];
            int s1 = ssrc[j1 < e1 ? j1 : 0];
            int s2 = ssrc[j2 < e2 ? j2 : 0];
            int s3 = ssrc[j3 < e3 ? j3 : 0];
            float g0 = __bfloat162float(h1s[(size_t)s0 * 64 + f]);
            float g1 = __bfloat162float(h1s[(size_t)s1 * 64 + f]);
            float g2 = __bfloat162float(h1s[(size_t)s2 * 64 + f]);
            float g3 = __bfloat162float(h1s[(size_t)s3 * 64 + f]);
            if (j0 < e0) a0 += g0;
            if (j1 < e1) a1 += g1;
            if (j2 < e2) a2 += g2;
            if (j3 < e3) a3 += g3;
        }
        float q0 = 0.f, q1 = 0.f, q2 = 0.f, q3 = 0.f;
#pragma unroll 8
        for (int k = 0; k < 64; ++k) {
            float w2v = W2[k * 64 + f];
            q0 += __shfl(a0, k) * w2v;
            q1 += __shfl(a1, k) * w2v;
            q2 += __shfl(a2, k) * w2v;
            q3 += __shfl(a3, k) * w2v;
        }
        psum += fmaxf(q0 * dinv[i0] + bf, 0.f);
        if (v1) psum += fmaxf(q1 * dinv[i1] + bf, 0.f);
        if (v2) psum += fmaxf(q2 * dinv[i2] + bf, 0.f);
        if (v3) psum += fmaxf(q3 * dinv[i3] + bf, 0.f);
    }
    atomicAdd(&red64[f], psum);
    __syncthreads();
    if (t < 64) atomicAdd(&red[(blockIdx.x & (RCOPY - 1)) * 64 + t], red64[t]);
}

// Final head: emb = [mean(h2), gf(6)] (70), MLP 70->32->2, 2+3*sigmoid.
// Sums the RCOPY accumulator copies and the per-block gf partials (1 wave).
__global__ void k_head(const float* __restrict__ red, const float* __restrict__ gfpart,
                       const float* __restrict__ l1w, const float* __restrict__ l1b,
                       const float* __restrict__ l2w, const float* __restrict__ l2b,
                       float* __restrict__ out, int n, int NBK) {
    __shared__ float emb[70];
    __shared__ float hid[32];
    int t = threadIdx.x;
    if (t < 64) {
        float s = 0.f;
#pragma unroll
        for (int c = 0; c < RCOPY; ++c) s += red[c * 64 + t];
        emb[t] = s / (float)n;
    }
    float g0 = 0.f, g1 = 0.f, g2 = 0.f, g3 = 0.f, g4 = 0.f, g5 = 0.f;
    for (int b = t; b < NBK; b += 64) {
        g0 += gfpart[b * 8 + 0]; g1 += gfpart[b * 8 + 1];
        g2 += gfpart[b * 8 + 2]; g3 += gfpart[b * 8 + 3];
        g4 += gfpart[b * 8 + 4]; g5 += gfpart[b * 8 + 5];
    }
#pragma unroll
    for (int off = 32; off; off >>= 1) {
        g0 += __shfl_down(g0, off); g1 += __shfl_down(g1, off);
        g2 += __shfl_down(g2, off); g3 += __shfl_down(g3, off);
        g4 += __shfl_down(g4, off); g5 += __shfl_down(g5, off);
    }
    if (t == 0) {
        float cnt = g5;
        float safe = fmaxf(cnt, 1.f);
        emb[64] = g0;                       // n_comp
        emb[65] = g1;                       // n_and
        emb[66] = g2;                       // n_or
        emb[67] = g1 + g2;                  // depth
        emb[68] = cnt > 0.f ? g3 / safe : 0.f;   // avg_lambda
        emb[69] = cnt > 0.f ? g4 / safe : 0.f;   // avg_mu
    }
    __syncthreads();
    if (t < 32) {
        float acc = l1b[t];
#pragma unroll
        for (int k = 0; k < 70; ++k) acc += emb[k] * l1w[k * 32 + t];
        hid[t] = fmaxf(acc, 0.f);
    }
    __syncthreads();
    if (t < 2) {
        float acc = l2b[t];
#pragma unroll
        for (int j = 0; j < 32; ++j) acc += hid[j] * l2w[j * 2 + t];
        out[t] = 2.0f + 3.0f / (1.0f + expf(-acc));
    }
}

extern "C" void kernel_launch(void* const* d_in, const int* in_sizes, int n_in,
                              void* d_out, int out_size, void* d_ws, size_t ws_size,
                              hipStream_t stream) {
    const float* x   = (const float*)d_in[0];
    const int*   ei  = (const int*)d_in[1];
    const float* w1  = (const float*)d_in[2];
    const float* b1  = (const float*)d_in[3];
    const float* w2  = (const float*)d_in[4];
    const float* b2  = (const float*)d_in[5];
    const float* l1w = (const float*)d_in[6];
    const float* l1b = (const float*)d_in[7];
    const float* l2w = (const float*)d_in[8];
    const float* l2b = (const float*)d_in[9];

    const int n = in_sizes[0] / 5;
    const int E = in_sizes[1] / 2;
    const int* src = ei;
    const int* dst = ei + E;

    const int NBK = (n + BUCKET - 1) / BUCKET;   // 391 buckets
    const int NCH = NCHV;                         // 2048 edge chunks
    const int chunk = (E + NCH - 1) / NCH;

    size_t nf = (size_t)n * 64;
    __hip_bfloat16* h1s = (__hip_bfloat16*)d_ws;      // N x 64 bf16 prescaled
    float* xs          = (float*)(h1s + nf);          // N x 8 (padded)
    float* agg5        = xs + (size_t)n * 8;          // N x 8 (padded)
    float* dinv        = agg5 + (size_t)n * 8;
    float* red         = dinv + n;                    // RCOPY*64 floats
    float* gfpart      = red + RCOPY * 64;            // NBK*8 floats
    int*   pos         = (int*)(gfpart + (MAXB * 8));
    int*   rowend      = pos + n;
    int*   btot        = rowend + n;                  // MAXB ints
    int*   bucket_base = btot + MAXB;                 // NBK+1
    int*   qhist       = bucket_base + (MAXB + 8);    // NBK*Q*256
    int*   qbase       = qhist + NBK * Q * BUCKET;    // NBK*Q*256
    int*   gcounts     = qbase + NBK * Q * BUCKET;    // NCH*NBK
    int*   records     = gcounts + NCH * NBK;         // E ints
    int*   ssrc        = records + E;                 // E ints, per-node CSR

    k_hist<<<NCH, 512, 0, stream>>>(dst, E, chunk, gcounts, NBK);
    k_colsum<<<NBK, 256, 0, stream>>>(gcounts, btot, NBK, NCH);
    k_scanA<<<1, MAXB, 0, stream>>>(btot, bucket_base, red, NBK);
    k_scanB<<<NBK, 512, 0, stream>>>(gcounts, bucket_base, NBK, NCH);
    k_bucketize<<<NCH, 512, 0, stream>>>(src, dst, E, chunk, gcounts, records, NBK);

    dim3 qgrid(NBK, Q);
    k_csrA<<<qgrid, 512, 0, stream>>>(records, bucket_base, qhist);
    k_csrB<<<NBK, BUCKET, 0, stream>>>(qhist, bucket_base, x, qbase, pos, rowend,
                                       dinv, xs, gfpart, n);
    k_csrC<<<qgrid, 512, 0, stream>>>(records, bucket_base, qbase, ssrc);

    k_agg5<<<(n + 255) / 256, 256, 0, stream>>>(pos, rowend, ssrc, dinv, xs, agg5, n);
    k_h1<<<(int)((nf + 255) / 256), 256, 0, stream>>>(agg5, w1, b1, dinv, h1s, n);
    k_l2fuse<<<4096, 256, 0, stream>>>(pos, rowend, ssrc, dinv, h1s, w2, b2, red, n);

    k_head<<<1, 64, 0, stream>>>(red, gfpart, l1w, l1b, l2w, l2b, (float*)d_out, n, NBK);
}